// Round 13
// baseline (98.287 us; speedup 1.0000x reference)
//
#include <hip/hip_runtime.h>
#include <hip/hip_bf16.h>

typedef __attribute__((ext_vector_type(8))) short short8;
typedef __attribute__((ext_vector_type(8))) unsigned short ushort8;
typedef __attribute__((ext_vector_type(4))) float f32x4;
typedef __attribute__((ext_vector_type(2))) float f32x2;
typedef __attribute__((ext_vector_type(4))) unsigned int uint4v;

#define DIM 128
#define EPS 1e-6f

__device__ __forceinline__ float wave_sum(float v){
  #pragma unroll
  for (int m = 32; m >= 1; m >>= 1) v += __shfl_xor(v, m);
  return v;
}

// block 0 = u1/u2/c12; blocks 1..64 = W^T bf16. (row_ptr lives in pack.)
__global__ void setup_kernel(const float* __restrict__ w_W,
                             const float* __restrict__ w1_W, const float* __restrict__ w1_b,
                             const float* __restrict__ w2_W, const float* __restrict__ w2_b,
                             __hip_bfloat16* __restrict__ wt_bf,
                             float* __restrict__ u1, float* __restrict__ u2,
                             float* __restrict__ c12){
  const int b = blockIdx.x, tid = threadIdx.x;
  if (b == 0){
    __shared__ float p1s[256], p2s[256];
    const int d = tid & 127, half = tid >> 7;       // half 0: j 0..63, half 1: j 64..127
    const float4* w1p = (const float4*)(w1_W + d*DIM + half*64);
    const float4* w2p = (const float4*)(w2_W + d*DIM + half*64);
    float s1 = 0.f, s2 = 0.f;
    #pragma unroll 4
    for (int j = 0; j < 16; ++j){
      float4 a = w1p[j]; s1 += (a.x + a.y) + (a.z + a.w);
      float4 c = w2p[j]; s2 += (c.x + c.y) + (c.z + c.w);
    }
    p1s[tid] = s1; p2s[tid] = s2;
    __syncthreads();
    if (tid < 128){ u1[tid] = p1s[tid] + p1s[tid+128]; u2[tid] = p2s[tid] + p2s[tid+128]; }
    if (tid < 64){
      float c1 = w1_b[tid] + w1_b[tid + 64];
      float c2 = w2_b[tid] + w2_b[tid + 64];
      c1 = wave_sum(c1); c2 = wave_sum(c2);
      if (tid == 0){ c12[0] = c1; c12[1] = c2; }
    }
  } else {
    int idx = (b - 1) * 256 + tid;
    int j = idx >> 7, d = idx & 127;
    wt_bf[idx] = __float2bfloat16(w_W[d*DIM + j]);
  }
}

// LN1 (16-lane group per node) + value = q@w_W + w_b (bf16 MFMA; wave = 32 rows x 64 cols)
// + per-row int8 quantization of value. Writes sum1, s2v = {tanh2, scale}.
__launch_bounds__(256)
__global__ void node_kernel(const float* __restrict__ query,
                            const __hip_bfloat16* __restrict__ wt_bf,
                            const float* __restrict__ w_b,
                            const float* __restrict__ ln1_g, const float* __restrict__ ln1_b,
                            const float* __restrict__ u1, const float* __restrict__ u2,
                            const float* __restrict__ c12,
                            unsigned char* __restrict__ value_q,
                            float* __restrict__ sum1, float2* __restrict__ s2v, int N){
  __shared__ __hip_bfloat16 A[64][136];    // +8 pad; row stride 272B (16B aligned)
  const int tid  = threadIdx.x;
  const int lane = tid & 63;
  const int w    = tid >> 6;
  const int q16  = lane >> 4;    // group 0..3
  const int lq   = lane & 15;    // lane in group
  const int base = blockIdx.x * 64;

  float uu1[8], uu2[8], gg[8], bv[8];
  {
    const float* p1 = u1 + lq*8; const float* p2 = u2 + lq*8;
    const float* pg = ln1_g + lq*8; const float* pb = ln1_b + lq*8;
    #pragma unroll
    for (int j = 0; j < 8; ++j){ uu1[j]=p1[j]; uu2[j]=p2[j]; gg[j]=pg[j]; bv[j]=pb[j]; }
  }
  const float c1 = c12[0], c2 = c12[1];

  // LN1: group q16 of wave w handles node base + w*16 + it*4 + q16
  #pragma unroll
  for (int it = 0; it < 4; ++it){
    const int row = w*16 + it*4 + q16;
    const int n   = base + row;
    float x[8];
    if (n < N){
      const float4* qp = (const float4*)(query + (size_t)n*DIM + lq*8);
      float4 a = qp[0], b = qp[1];
      x[0]=a.x; x[1]=a.y; x[2]=a.z; x[3]=a.w;
      x[4]=b.x; x[5]=b.y; x[6]=b.z; x[7]=b.w;
    } else {
      #pragma unroll
      for (int j = 0; j < 8; ++j) x[j] = 0.f;
    }
    float s = 0.f, s2 = 0.f;
    #pragma unroll
    for (int j = 0; j < 8; ++j){ s += x[j]; s2 += x[j]*x[j]; }
    #pragma unroll
    for (int m = 1; m <= 8; m <<= 1){ s += __shfl_xor(s, m); s2 += __shfl_xor(s2, m); }
    const float mean = s * (1.f/128.f);
    const float var  = s2 * (1.f/128.f) - mean*mean;
    const float rs   = rsqrtf(var + EPS);

    float p1 = 0.f, p2 = 0.f;
    unsigned pk[4];
    #pragma unroll
    for (int j = 0; j < 4; ++j){
      float n0 = gg[2*j]   * (x[2*j]   - mean) * rs + bv[2*j];
      float n1 = gg[2*j+1] * (x[2*j+1] - mean) * rs + bv[2*j+1];
      p1 += n0*uu1[2*j] + n1*uu1[2*j+1];
      p2 += n0*uu2[2*j] + n1*uu2[2*j+1];
      union { __hip_bfloat16 h; unsigned short u; } a_, b_;
      a_.h = __float2bfloat16(n0); b_.h = __float2bfloat16(n1);
      pk[j] = ((unsigned)b_.u << 16) | (unsigned)a_.u;
    }
    uint4v pv = { pk[0], pk[1], pk[2], pk[3] };
    *(uint4v*)&A[row][lq*8] = pv;
    #pragma unroll
    for (int m = 1; m <= 8; m <<= 1){ p1 += __shfl_xor(p1, m); p2 += __shfl_xor(p2, m); }
    // branchless dual-tanh: lanes 0/1 each compute one tanh in parallel
    if (lq < 2 && n < N){
      const float arg = (lq == 0) ? (p1 + c1) : (p2 + c2);
      const float th = tanhf(arg);
      if (lq == 0) sum1[n] = th;
      else        s2v[n].x = th;
    }
  }
  __syncthreads();

  // GEMM: wave w: rows [(w&1)*32, +32) x cols [(w>>1)*64, +64); 2 MFMA per B-load
  const int rh = (w & 1) * 32;
  const int ch = (w >> 1) * 64;
  short8 afr[2][4];
  #pragma unroll
  for (int m = 0; m < 2; ++m)
    #pragma unroll
    for (int ks = 0; ks < 4; ++ks)
      afr[m][ks] = *(const short8*)&A[rh + m*16 + lq][ks*32 + q16*8];
  __syncthreads();   // all waves done reading A before C overwrites it

  #pragma unroll
  for (int jj = 0; jj < 4; ++jj){
    const int colb = ch + jj*16;
    f32x4 acc[2];
    acc[0] = (f32x4){0.f,0.f,0.f,0.f};
    acc[1] = (f32x4){0.f,0.f,0.f,0.f};
    #pragma unroll
    for (int ks = 0; ks < 4; ++ks){
      short8 bfr = *(const short8*)(wt_bf + (size_t)(colb + lq)*DIM + ks*32 + q16*8);
      acc[0] = __builtin_amdgcn_mfma_f32_16x16x32_bf16(afr[0][ks], bfr, acc[0], 0, 0, 0);
      acc[1] = __builtin_amdgcn_mfma_f32_16x16x32_bf16(afr[1][ks], bfr, acc[1], 0, 0, 0);
    }
    const int col  = colb + lq;            // C/D: col = lane&15, row = (lane>>4)*4 + reg
    const float bias = w_b[col];
    #pragma unroll
    for (int m = 0; m < 2; ++m)
      #pragma unroll
      for (int i = 0; i < 4; ++i)
        A[rh + m*16 + q16*4 + i][col] = __float2bfloat16(acc[m][i] + bias);
  }
  __syncthreads();

  // int8 quantize + store: 4 threads per row; vectorized ds_read_b128 (16B x4)
  const int row = tid >> 2, seg = tid & 3;
  const int n = base + row;
  float vals[32];
  float amax = 0.f;
  const ushort8* ap = (const ushort8*)&A[row][seg*32];
  #pragma unroll
  for (int h = 0; h < 4; ++h){
    ushort8 vv = ap[h];
    #pragma unroll
    for (int j = 0; j < 8; ++j){
      float f = __uint_as_float((unsigned)vv[j] << 16);
      vals[h*8 + j] = f;
      amax = fmaxf(amax, fabsf(f));
    }
  }
  amax = fmaxf(amax, __shfl_xor(amax, 1));
  amax = fmaxf(amax, __shfl_xor(amax, 2));
  const float qs = amax > 0.f ? 127.f / amax : 0.f;
  if (n < N){
    if (seg == 0) s2v[n].y = amax * (1.f/127.f);
    unsigned dw[8];
    #pragma unroll
    for (int d = 0; d < 8; ++d){
      unsigned q0 = (unsigned)__float2int_rn(fmaf(vals[4*d+0], qs, 128.f));
      unsigned q1 = (unsigned)__float2int_rn(fmaf(vals[4*d+1], qs, 128.f));
      unsigned q2 = (unsigned)__float2int_rn(fmaf(vals[4*d+2], qs, 128.f));
      unsigned q3 = (unsigned)__float2int_rn(fmaf(vals[4*d+3], qs, 128.f));
      dw[d] = q0 | (q1 << 8) | (q2 << 16) | (q3 << 24);
    }
    uint4v* dst = (uint4v*)(value_q + (size_t)n*DIM + seg*32);
    dst[0] = (uint4v){dw[0], dw[1], dw[2], dw[3]};
    dst[1] = (uint4v){dw[4], dw[5], dw[6], dw[7]};
  }
}

// 4 edges/thread, vectorized: int4/float4 loads, 4 independent s2v gathers in
// flight, float4 excol stores. Also builds row_ptr via boundary detect (adj_row
// sorted). Per-edge math identical (order-preserved) to the 1-edge version.
__global__ void pack_kernel(const float* __restrict__ adj_val, const int* __restrict__ adj_row,
                            const int* __restrict__ adj_col,
                            const float* __restrict__ sum1, const float2* __restrict__ s2v,
                            float2* __restrict__ excol, int* __restrict__ row_ptr,
                            int N, int E){
  const int e4 = (blockIdx.x * 256 + threadIdx.x) * 4;
  if (e4 >= E) return;

  if (e4 + 3 < E){
    const int4   rr = *(const int4*)(adj_row + e4);
    const float4 av = *(const float4*)(adj_val + e4);
    const int4   cc = *(const int4*)(adj_col + e4);

    // row_ptr boundaries (adj_row sorted)
    const int prev = (e4 > 0) ? adj_row[e4 - 1] : -1;
    if (prev != rr.x) for (int t = prev + 1; t <= rr.x; ++t) row_ptr[t] = e4;
    if (rr.y != rr.x) for (int t = rr.x + 1; t <= rr.y; ++t) row_ptr[t] = e4 + 1;
    if (rr.z != rr.y) for (int t = rr.y + 1; t <= rr.z; ++t) row_ptr[t] = e4 + 2;
    if (rr.w != rr.z) for (int t = rr.z + 1; t <= rr.w; ++t) row_ptr[t] = e4 + 3;
    if (e4 + 4 >= E)  for (int t = rr.w + 1; t <= N;    ++t) row_ptr[t] = E;

    // 4 independent gathers
    const float2 sv0 = s2v[cc.x];
    const float2 sv1 = s2v[cc.y];
    const float2 sv2 = s2v[cc.z];
    const float2 sv3 = s2v[cc.w];
    const float s10 = sum1[rr.x];
    const float s11 = sum1[rr.y];
    const float s12 = sum1[rr.z];
    const float s13 = sum1[rr.w];

    float x0 = av.x * (s10 + sv0.x); float l0 = x0 > 0.f ? x0 : 0.2f * x0;
    float x1 = av.y * (s11 + sv1.x); float l1 = x1 > 0.f ? x1 : 0.2f * x1;
    float x2 = av.z * (s12 + sv2.x); float l2 = x2 > 0.f ? x2 : 0.2f * x2;
    float x3 = av.w * (s13 + sv3.x); float l3 = x3 > 0.f ? x3 : 0.2f * x3;

    float4* dst = (float4*)(excol + e4);
    dst[0] = make_float4(__expf(l0) * sv0.y, __int_as_float(cc.x << 7),
                         __expf(l1) * sv1.y, __int_as_float(cc.y << 7));
    dst[1] = make_float4(__expf(l2) * sv2.y, __int_as_float(cc.z << 7),
                         __expf(l3) * sv3.y, __int_as_float(cc.w << 7));
  } else {
    // generic tail (E not multiple of 4)
    int last_r = -1;
    for (int e = e4; e < E; ++e){
      const int r = adj_row[e];
      const int prev = (e > 0) ? adj_row[e - 1] : -1;
      if (prev != r) for (int t = prev + 1; t <= r; ++t) row_ptr[t] = e;
      const int c = adj_col[e];
      const float2 sv = s2v[c];
      const float x = adj_val[e] * (sum1[r] + sv.x);
      const float lg = x > 0.f ? x : 0.2f * x;
      excol[e] = make_float2(__expf(lg) * sv.y, __int_as_float(c << 7));
      last_r = r;
    }
    if (last_r >= 0) for (int t = last_r + 1; t <= N; ++t) row_ptr[t] = E;
  }
}

// TWO rows per wave; 16-edge main blocks (8 independent excol->value chains per
// lane — doubled MLP to hide L3 latency on the 12.8MB value table), then 8-block,
// then guarded tail. Accumulation order per accumulator identical to 8-blocks
// (t ascending, stride 2) -> bitwise-same output. Single pass (LN2 scale-
// invariance cancels softmax 1/s; +128 offset cancels in mean-subtraction).
__launch_bounds__(256)
__global__ void edge_kernel(const float2* __restrict__ excol, const int* __restrict__ row_ptr,
                            const unsigned char* __restrict__ value_q,
                            const float* __restrict__ ln2_g, const float* __restrict__ ln2_b,
                            float* __restrict__ out, int N){
  const int lane = threadIdx.x & 63;
  const int half = lane >> 5;          // row within the wave's pair
  const int ll   = lane & 31;
  const int q2   = ll >> 4;            // quarter within row (0/1)
  const int lq   = ll & 15;            // owns dims [8*lq, 8*lq+8)
  const int r = blockIdx.x * 8 + (threadIdx.x >> 6) * 2 + half;
  if (r >= N) return;
  const int2 rp = *(const int2*)(row_ptr + r);   // e0, e1
  const int e0 = rp.x, e1 = rp.y;
  const unsigned char* vbase = value_q + lq*8;

  f32x2 acc2[4];
  #pragma unroll
  for (int j = 0; j < 4; ++j) acc2[j] = (f32x2){0.f, 0.f};

  int sb = e0;
  for (; sb + 16 <= e1; sb += 16){         // 16-blocks: 8 chains in flight
    float2 ecv[8];
    #pragma unroll
    for (int t = 0; t < 8; ++t) ecv[t] = excol[sb + q2 + t*2];
    #pragma unroll
    for (int t = 0; t < 8; ++t){
      const float wsc = ecv[t].x;
      const unsigned voff = (unsigned)__float_as_int(ecv[t].y);
      uint2 v = *(const uint2*)(vbase + voff);
      f32x2 w2 = { wsc, wsc };
      f32x2 p0 = { (float)( v.x        & 0xff), (float)((v.x >>  8) & 0xff) };
      f32x2 p1 = { (float)((v.x >> 16) & 0xff), (float)( v.x >> 24)         };
      f32x2 p2 = { (float)( v.y        & 0xff), (float)((v.y >>  8) & 0xff) };
      f32x2 p3 = { (float)((v.y >> 16) & 0xff), (float)( v.y >> 24)         };
      acc2[0] += w2 * p0;
      acc2[1] += w2 * p1;
      acc2[2] += w2 * p2;
      acc2[3] += w2 * p3;
    }
  }
  for (; sb + 8 <= e1; sb += 8){           // full 8-blocks: no guards
    #pragma unroll
    for (int t = 0; t < 4; ++t){
      float2 ecv = excol[sb + q2 + t*2];
      const float wsc = ecv.x;
      const unsigned voff = (unsigned)__float_as_int(ecv.y);
      uint2 v = *(const uint2*)(vbase + voff);
      f32x2 w2 = { wsc, wsc };
      f32x2 p0 = { (float)( v.x        & 0xff), (float)((v.x >>  8) & 0xff) };
      f32x2 p1 = { (float)((v.x >> 16) & 0xff), (float)( v.x >> 24)         };
      f32x2 p2 = { (float)( v.y        & 0xff), (float)((v.y >>  8) & 0xff) };
      f32x2 p3 = { (float)((v.y >> 16) & 0xff), (float)( v.y >> 24)         };
      acc2[0] += w2 * p0;
      acc2[1] += w2 * p1;
      acc2[2] += w2 * p2;
      acc2[3] += w2 * p3;
    }
  }
  if (sb < e1){                             // guarded tail (cnt%8 slots)
    #pragma unroll
    for (int t = 0; t < 4; ++t){
      const int e = sb + q2 + t*2;
      float2 ecv = (e < e1) ? excol[e] : make_float2(0.f, 0.f);  // voff 0 safe
      const float wsc = ecv.x;
      const unsigned voff = (unsigned)__float_as_int(ecv.y);
      uint2 v = *(const uint2*)(vbase + voff);
      f32x2 w2 = { wsc, wsc };
      f32x2 p0 = { (float)( v.x        & 0xff), (float)((v.x >>  8) & 0xff) };
      f32x2 p1 = { (float)((v.x >> 16) & 0xff), (float)( v.x >> 24)         };
      f32x2 p2 = { (float)( v.y        & 0xff), (float)((v.y >>  8) & 0xff) };
      f32x2 p3 = { (float)((v.y >> 16) & 0xff), (float)( v.y >> 24)         };
      acc2[0] += w2 * p0;
      acc2[1] += w2 * p1;
      acc2[2] += w2 * p2;
      acc2[3] += w2 * p3;
    }
  }

  // reduce across the 2 quarters of this row (stays within the 32-lane half)
  #pragma unroll
  for (int j = 0; j < 4; ++j){
    acc2[j].x += __shfl_xor(acc2[j].x, 16);
    acc2[j].y += __shfl_xor(acc2[j].y, 16);
  }

  // single-pass LN2 stats over the 16-lane dim groups (both rows simultaneously)
  float sx = 0.f, sxx = 0.f;
  #pragma unroll
  for (int j = 0; j < 4; ++j){
    sx  += acc2[j].x + acc2[j].y;
    sxx += acc2[j].x*acc2[j].x + acc2[j].y*acc2[j].y;
  }
  #pragma unroll
  for (int m = 1; m <= 8; m <<= 1){ sx += __shfl_xor(sx, m); sxx += __shfl_xor(sxx, m); }
  const float mean = sx * (1.f/128.f);
  const float var  = sxx * (1.f/128.f) - mean*mean;
  const float rs   = rsqrtf(var + EPS);

  if (q2 == 0){
    float4 g0 = ((const float4*)ln2_g)[lq*2], g1 = ((const float4*)ln2_g)[lq*2+1];
    float4 b0 = ((const float4*)ln2_b)[lq*2], b1 = ((const float4*)ln2_b)[lq*2+1];
    float4 o0, o1;
    o0.x = g0.x*(acc2[0].x-mean)*rs + b0.x; o0.y = g0.y*(acc2[0].y-mean)*rs + b0.y;
    o0.z = g0.z*(acc2[1].x-mean)*rs + b0.z; o0.w = g0.w*(acc2[1].y-mean)*rs + b0.w;
    o1.x = g1.x*(acc2[2].x-mean)*rs + b1.x; o1.y = g1.y*(acc2[2].y-mean)*rs + b1.y;
    o1.z = g1.z*(acc2[3].x-mean)*rs + b1.z; o1.w = g1.w*(acc2[3].y-mean)*rs + b1.w;
    float4* op = (float4*)(out + (size_t)r*DIM + lq*8);
    op[0] = o0; op[1] = o1;
  }
}

extern "C" void kernel_launch(void* const* d_in, const int* in_sizes, int n_in,
                              void* d_out, int out_size, void* d_ws, size_t ws_size,
                              hipStream_t stream){
  const float* query   = (const float*)d_in[0];
  const float* adj_val = (const float*)d_in[1];
  const float* w_W     = (const float*)d_in[2];
  const float* w_b     = (const float*)d_in[3];
  const float* w1_W    = (const float*)d_in[4];
  const float* w1_b    = (const float*)d_in[5];
  const float* w2_W    = (const float*)d_in[6];
  const float* w2_b    = (const float*)d_in[7];
  const float* ln1_g   = (const float*)d_in[8];
  const float* ln1_b   = (const float*)d_in[9];
  const float* ln2_g   = (const float*)d_in[10];
  const float* ln2_b   = (const float*)d_in[11];
  const int*   adj_row = (const int*)d_in[12];
  const int*   adj_col = (const int*)d_in[13];

  const int N = in_sizes[0] / DIM;
  const int E = in_sizes[1];

  char* ws = (char*)d_ws;
  size_t off = 0;
  unsigned char* value_q = (unsigned char*)(ws + off); off += (size_t)N * DIM;
  float* sum1   = (float*)(ws + off); off += (size_t)N * 4;
  float2* s2v   = (float2*)(ws + off); off += (size_t)N * 8;
  int* row_ptr  = (int*)(ws + off);   off += (size_t)(N + 2) * 4;
  float* u1     = (float*)(ws + off); off += DIM * 4;
  float* u2     = (float*)(ws + off); off += DIM * 4;
  float* c12    = (float*)(ws + off); off += 2 * 4;
  off = (off + 63) & ~(size_t)63;
  __hip_bfloat16* wt_bf = (__hip_bfloat16*)(ws + off); off += DIM * DIM * 2;
  off = (off + 63) & ~(size_t)63;
  float2* excol = (float2*)(ws + off);

  setup_kernel<<<65, 256, 0, stream>>>(w_W, w1_W, w1_b, w2_W, w2_b, wt_bf, u1, u2, c12);
  node_kernel<<<(N + 63) / 64, 256, 0, stream>>>(query, wt_bf, w_b, ln1_g, ln1_b,
                                                 u1, u2, c12, value_q, sum1, s2v, N);
  pack_kernel<<<(E/4 + 255) / 256, 256, 0, stream>>>(adj_val, adj_row, adj_col,
                                                     sum1, s2v, excol, row_ptr, N, E);
  edge_kernel<<<(N + 7) / 8, 256, 0, stream>>>(excol, row_ptr, value_q,
                                               ln2_g, ln2_b, (float*)d_out, N);
}

// Round 14
// 96.490 us; speedup vs baseline: 1.0186x; 1.0186x over previous
//
#include <hip/hip_runtime.h>
#include <hip/hip_bf16.h>

typedef __attribute__((ext_vector_type(8))) short short8;
typedef __attribute__((ext_vector_type(8))) unsigned short ushort8;
typedef __attribute__((ext_vector_type(4))) float f32x4;
typedef __attribute__((ext_vector_type(2))) float f32x2;
typedef __attribute__((ext_vector_type(4))) unsigned int uint4v;

#define DIM 128
#define EPS 1e-6f

__device__ __forceinline__ float wave_sum(float v){
  #pragma unroll
  for (int m = 32; m >= 1; m >>= 1) v += __shfl_xor(v, m);
  return v;
}

// block 0 = u1/u2/c12; blocks 1..64 = W^T bf16. (row_ptr lives in pack.)
__global__ void setup_kernel(const float* __restrict__ w_W,
                             const float* __restrict__ w1_W, const float* __restrict__ w1_b,
                             const float* __restrict__ w2_W, const float* __restrict__ w2_b,
                             __hip_bfloat16* __restrict__ wt_bf,
                             float* __restrict__ u1, float* __restrict__ u2,
                             float* __restrict__ c12){
  const int b = blockIdx.x, tid = threadIdx.x;
  if (b == 0){
    __shared__ float p1s[256], p2s[256];
    const int d = tid & 127, half = tid >> 7;       // half 0: j 0..63, half 1: j 64..127
    const float4* w1p = (const float4*)(w1_W + d*DIM + half*64);
    const float4* w2p = (const float4*)(w2_W + d*DIM + half*64);
    float s1 = 0.f, s2 = 0.f;
    #pragma unroll 4
    for (int j = 0; j < 16; ++j){
      float4 a = w1p[j]; s1 += (a.x + a.y) + (a.z + a.w);
      float4 c = w2p[j]; s2 += (c.x + c.y) + (c.z + c.w);
    }
    p1s[tid] = s1; p2s[tid] = s2;
    __syncthreads();
    if (tid < 128){ u1[tid] = p1s[tid] + p1s[tid+128]; u2[tid] = p2s[tid] + p2s[tid+128]; }
    if (tid < 64){
      float c1 = w1_b[tid] + w1_b[tid + 64];
      float c2 = w2_b[tid] + w2_b[tid + 64];
      c1 = wave_sum(c1); c2 = wave_sum(c2);
      if (tid == 0){ c12[0] = c1; c12[1] = c2; }
    }
  } else {
    int idx = (b - 1) * 256 + tid;
    int j = idx >> 7, d = idx & 127;
    wt_bf[idx] = __float2bfloat16(w_W[d*DIM + j]);
  }
}

// LN1 (16-lane group per node) + value = q@w_W + w_b (bf16 MFMA; wave = 32 rows x 64 cols)
// + per-row int8 quantization of value. Writes sum1, s2v = {tanh2, scale}.
__launch_bounds__(256)
__global__ void node_kernel(const float* __restrict__ query,
                            const __hip_bfloat16* __restrict__ wt_bf,
                            const float* __restrict__ w_b,
                            const float* __restrict__ ln1_g, const float* __restrict__ ln1_b,
                            const float* __restrict__ u1, const float* __restrict__ u2,
                            const float* __restrict__ c12,
                            unsigned char* __restrict__ value_q,
                            float* __restrict__ sum1, float2* __restrict__ s2v, int N){
  __shared__ __hip_bfloat16 A[64][136];    // +8 pad; row stride 272B (16B aligned)
  const int tid  = threadIdx.x;
  const int lane = tid & 63;
  const int w    = tid >> 6;
  const int q16  = lane >> 4;    // group 0..3
  const int lq   = lane & 15;    // lane in group
  const int base = blockIdx.x * 64;

  float uu1[8], uu2[8], gg[8], bv[8];
  {
    const float* p1 = u1 + lq*8; const float* p2 = u2 + lq*8;
    const float* pg = ln1_g + lq*8; const float* pb = ln1_b + lq*8;
    #pragma unroll
    for (int j = 0; j < 8; ++j){ uu1[j]=p1[j]; uu2[j]=p2[j]; gg[j]=pg[j]; bv[j]=pb[j]; }
  }
  const float c1 = c12[0], c2 = c12[1];

  // LN1: group q16 of wave w handles node base + w*16 + it*4 + q16
  #pragma unroll
  for (int it = 0; it < 4; ++it){
    const int row = w*16 + it*4 + q16;
    const int n   = base + row;
    float x[8];
    if (n < N){
      const float4* qp = (const float4*)(query + (size_t)n*DIM + lq*8);
      float4 a = qp[0], b = qp[1];
      x[0]=a.x; x[1]=a.y; x[2]=a.z; x[3]=a.w;
      x[4]=b.x; x[5]=b.y; x[6]=b.z; x[7]=b.w;
    } else {
      #pragma unroll
      for (int j = 0; j < 8; ++j) x[j] = 0.f;
    }
    float s = 0.f, s2 = 0.f;
    #pragma unroll
    for (int j = 0; j < 8; ++j){ s += x[j]; s2 += x[j]*x[j]; }
    #pragma unroll
    for (int m = 1; m <= 8; m <<= 1){ s += __shfl_xor(s, m); s2 += __shfl_xor(s2, m); }
    const float mean = s * (1.f/128.f);
    const float var  = s2 * (1.f/128.f) - mean*mean;
    const float rs   = rsqrtf(var + EPS);

    float p1 = 0.f, p2 = 0.f;
    unsigned pk[4];
    #pragma unroll
    for (int j = 0; j < 4; ++j){
      float n0 = gg[2*j]   * (x[2*j]   - mean) * rs + bv[2*j];
      float n1 = gg[2*j+1] * (x[2*j+1] - mean) * rs + bv[2*j+1];
      p1 += n0*uu1[2*j] + n1*uu1[2*j+1];
      p2 += n0*uu2[2*j] + n1*uu2[2*j+1];
      union { __hip_bfloat16 h; unsigned short u; } a_, b_;
      a_.h = __float2bfloat16(n0); b_.h = __float2bfloat16(n1);
      pk[j] = ((unsigned)b_.u << 16) | (unsigned)a_.u;
    }
    uint4v pv = { pk[0], pk[1], pk[2], pk[3] };
    *(uint4v*)&A[row][lq*8] = pv;
    #pragma unroll
    for (int m = 1; m <= 8; m <<= 1){ p1 += __shfl_xor(p1, m); p2 += __shfl_xor(p2, m); }
    // branchless dual-tanh: lanes 0/1 each compute one tanh in parallel
    if (lq < 2 && n < N){
      const float arg = (lq == 0) ? (p1 + c1) : (p2 + c2);
      const float th = tanhf(arg);
      if (lq == 0) sum1[n] = th;
      else        s2v[n].x = th;
    }
  }
  __syncthreads();

  // GEMM: wave w: rows [(w&1)*32, +32) x cols [(w>>1)*64, +64); 2 MFMA per B-load
  const int rh = (w & 1) * 32;
  const int ch = (w >> 1) * 64;
  short8 afr[2][4];
  #pragma unroll
  for (int m = 0; m < 2; ++m)
    #pragma unroll
    for (int ks = 0; ks < 4; ++ks)
      afr[m][ks] = *(const short8*)&A[rh + m*16 + lq][ks*32 + q16*8];
  __syncthreads();   // all waves done reading A before C overwrites it

  #pragma unroll
  for (int jj = 0; jj < 4; ++jj){
    const int colb = ch + jj*16;
    f32x4 acc[2];
    acc[0] = (f32x4){0.f,0.f,0.f,0.f};
    acc[1] = (f32x4){0.f,0.f,0.f,0.f};
    #pragma unroll
    for (int ks = 0; ks < 4; ++ks){
      short8 bfr = *(const short8*)(wt_bf + (size_t)(colb + lq)*DIM + ks*32 + q16*8);
      acc[0] = __builtin_amdgcn_mfma_f32_16x16x32_bf16(afr[0][ks], bfr, acc[0], 0, 0, 0);
      acc[1] = __builtin_amdgcn_mfma_f32_16x16x32_bf16(afr[1][ks], bfr, acc[1], 0, 0, 0);
    }
    const int col  = colb + lq;            // C/D: col = lane&15, row = (lane>>4)*4 + reg
    const float bias = w_b[col];
    #pragma unroll
    for (int m = 0; m < 2; ++m)
      #pragma unroll
      for (int i = 0; i < 4; ++i)
        A[rh + m*16 + q16*4 + i][col] = __float2bfloat16(acc[m][i] + bias);
  }
  __syncthreads();

  // int8 quantize + store: 4 threads per row; vectorized ds_read_b128 (16B x4)
  const int row = tid >> 2, seg = tid & 3;
  const int n = base + row;
  float vals[32];
  float amax = 0.f;
  const ushort8* ap = (const ushort8*)&A[row][seg*32];
  #pragma unroll
  for (int h = 0; h < 4; ++h){
    ushort8 vv = ap[h];
    #pragma unroll
    for (int j = 0; j < 8; ++j){
      float f = __uint_as_float((unsigned)vv[j] << 16);
      vals[h*8 + j] = f;
      amax = fmaxf(amax, fabsf(f));
    }
  }
  amax = fmaxf(amax, __shfl_xor(amax, 1));
  amax = fmaxf(amax, __shfl_xor(amax, 2));
  const float qs = amax > 0.f ? 127.f / amax : 0.f;
  if (n < N){
    if (seg == 0) s2v[n].y = amax * (1.f/127.f);
    unsigned dw[8];
    #pragma unroll
    for (int d = 0; d < 8; ++d){
      unsigned q0 = (unsigned)__float2int_rn(fmaf(vals[4*d+0], qs, 128.f));
      unsigned q1 = (unsigned)__float2int_rn(fmaf(vals[4*d+1], qs, 128.f));
      unsigned q2 = (unsigned)__float2int_rn(fmaf(vals[4*d+2], qs, 128.f));
      unsigned q3 = (unsigned)__float2int_rn(fmaf(vals[4*d+3], qs, 128.f));
      dw[d] = q0 | (q1 << 8) | (q2 << 16) | (q3 << 24);
    }
    uint4v* dst = (uint4v*)(value_q + (size_t)n*DIM + seg*32);
    dst[0] = (uint4v){dw[0], dw[1], dw[2], dw[3]};
    dst[1] = (uint4v){dw[4], dw[5], dw[6], dw[7]};
  }
}

// 8 edges/thread, flat: 8 independent s2v gathers in flight (named scalars, no
// arrays/loops -> compiler keeps chains parallel). Builds row_ptr via boundary
// detect (adj_row sorted). Per-edge math identical to the 1-edge version.
__global__ void pack_kernel(const float* __restrict__ adj_val, const int* __restrict__ adj_row,
                            const int* __restrict__ adj_col,
                            const float* __restrict__ sum1, const float2* __restrict__ s2v,
                            float2* __restrict__ excol, int* __restrict__ row_ptr,
                            int N, int E){
  const int e8 = (blockIdx.x * 256 + threadIdx.x) * 8;
  if (e8 >= E) return;

  if (e8 + 7 < E){
    const int4   ra = *(const int4*)(adj_row + e8);
    const int4   rb = *(const int4*)(adj_row + e8 + 4);
    const float4 va = *(const float4*)(adj_val + e8);
    const float4 vb = *(const float4*)(adj_val + e8 + 4);
    const int4   ca = *(const int4*)(adj_col + e8);
    const int4   cb = *(const int4*)(adj_col + e8 + 4);

    // row_ptr boundaries (adj_row sorted)
    const int prev = (e8 > 0) ? adj_row[e8 - 1] : -1;
    if (prev != ra.x) for (int t = prev + 1; t <= ra.x; ++t) row_ptr[t] = e8;
    if (ra.y != ra.x) for (int t = ra.x + 1; t <= ra.y; ++t) row_ptr[t] = e8 + 1;
    if (ra.z != ra.y) for (int t = ra.y + 1; t <= ra.z; ++t) row_ptr[t] = e8 + 2;
    if (ra.w != ra.z) for (int t = ra.z + 1; t <= ra.w; ++t) row_ptr[t] = e8 + 3;
    if (rb.x != ra.w) for (int t = ra.w + 1; t <= rb.x; ++t) row_ptr[t] = e8 + 4;
    if (rb.y != rb.x) for (int t = rb.x + 1; t <= rb.y; ++t) row_ptr[t] = e8 + 5;
    if (rb.z != rb.y) for (int t = rb.y + 1; t <= rb.z; ++t) row_ptr[t] = e8 + 6;
    if (rb.w != rb.z) for (int t = rb.z + 1; t <= rb.w; ++t) row_ptr[t] = e8 + 7;
    if (e8 + 8 >= E)  for (int t = rb.w + 1; t <= N;    ++t) row_ptr[t] = E;

    // 8 independent gathers in flight
    const float2 sv0 = s2v[ca.x];
    const float2 sv1 = s2v[ca.y];
    const float2 sv2 = s2v[ca.z];
    const float2 sv3 = s2v[ca.w];
    const float2 sv4 = s2v[cb.x];
    const float2 sv5 = s2v[cb.y];
    const float2 sv6 = s2v[cb.z];
    const float2 sv7 = s2v[cb.w];
    const float s10 = sum1[ra.x];
    const float s11 = sum1[ra.y];
    const float s12 = sum1[ra.z];
    const float s13 = sum1[ra.w];
    const float s14 = sum1[rb.x];
    const float s15 = sum1[rb.y];
    const float s16 = sum1[rb.z];
    const float s17 = sum1[rb.w];

    float x0 = va.x * (s10 + sv0.x); float l0 = x0 > 0.f ? x0 : 0.2f * x0;
    float x1 = va.y * (s11 + sv1.x); float l1 = x1 > 0.f ? x1 : 0.2f * x1;
    float x2 = va.z * (s12 + sv2.x); float l2 = x2 > 0.f ? x2 : 0.2f * x2;
    float x3 = va.w * (s13 + sv3.x); float l3 = x3 > 0.f ? x3 : 0.2f * x3;
    float x4 = vb.x * (s14 + sv4.x); float l4 = x4 > 0.f ? x4 : 0.2f * x4;
    float x5 = vb.y * (s15 + sv5.x); float l5 = x5 > 0.f ? x5 : 0.2f * x5;
    float x6 = vb.z * (s16 + sv6.x); float l6 = x6 > 0.f ? x6 : 0.2f * x6;
    float x7 = vb.w * (s17 + sv7.x); float l7 = x7 > 0.f ? x7 : 0.2f * x7;

    float4* dst = (float4*)(excol + e8);
    dst[0] = make_float4(__expf(l0) * sv0.y, __int_as_float(ca.x << 7),
                         __expf(l1) * sv1.y, __int_as_float(ca.y << 7));
    dst[1] = make_float4(__expf(l2) * sv2.y, __int_as_float(ca.z << 7),
                         __expf(l3) * sv3.y, __int_as_float(ca.w << 7));
    dst[2] = make_float4(__expf(l4) * sv4.y, __int_as_float(cb.x << 7),
                         __expf(l5) * sv5.y, __int_as_float(cb.y << 7));
    dst[3] = make_float4(__expf(l6) * sv6.y, __int_as_float(cb.z << 7),
                         __expf(l7) * sv7.y, __int_as_float(cb.w << 7));
  } else {
    // generic tail (E not multiple of 8)
    int last_r = -1;
    for (int e = e8; e < E; ++e){
      const int r = adj_row[e];
      const int prev = (e > 0) ? adj_row[e - 1] : -1;
      if (prev != r) for (int t = prev + 1; t <= r; ++t) row_ptr[t] = e;
      const int c = adj_col[e];
      const float2 sv = s2v[c];
      const float x = adj_val[e] * (sum1[r] + sv.x);
      const float lg = x > 0.f ? x : 0.2f * x;
      excol[e] = make_float2(__expf(lg) * sv.y, __int_as_float(c << 7));
      last_r = r;
    }
    if (last_r >= 0) for (int t = last_r + 1; t <= N; ++t) row_ptr[t] = E;
  }
}

// TWO rows per wave (lanes 0-31 = row A, 32-63 = row B); 2 sixteen-lane quarters
// per row -> block granularity 8 edges; R11-exact loop (proven: compiler pipelines
// the 4 unrolled chains; deeper variants serialize — R13 lesson). Single pass
// (LN2 scale-invariance cancels softmax 1/s; +128 quant offset cancels in
// mean-subtraction). All shuffles stay within 32-lane halves.
__launch_bounds__(256)
__global__ void edge_kernel(const float2* __restrict__ excol, const int* __restrict__ row_ptr,
                            const unsigned char* __restrict__ value_q,
                            const float* __restrict__ ln2_g, const float* __restrict__ ln2_b,
                            float* __restrict__ out, int N){
  const int lane = threadIdx.x & 63;
  const int half = lane >> 5;          // row within the wave's pair
  const int ll   = lane & 31;
  const int q2   = ll >> 4;            // quarter within row (0/1)
  const int lq   = ll & 15;            // owns dims [8*lq, 8*lq+8)
  const int r = blockIdx.x * 8 + (threadIdx.x >> 6) * 2 + half;
  if (r >= N) return;
  const int2 rp = *(const int2*)(row_ptr + r);   // e0, e1
  const int e0 = rp.x, e1 = rp.y;
  const unsigned char* vbase = value_q + lq*8;

  f32x2 acc2[4];
  #pragma unroll
  for (int j = 0; j < 4; ++j) acc2[j] = (f32x2){0.f, 0.f};

  int sb = e0;
  for (; sb + 8 <= e1; sb += 8){           // full 8-blocks: no guards
    #pragma unroll
    for (int t = 0; t < 4; ++t){
      float2 ecv = excol[sb + q2 + t*2];
      const float wsc = ecv.x;
      const unsigned voff = (unsigned)__float_as_int(ecv.y);
      uint2 v = *(const uint2*)(vbase + voff);
      f32x2 w2 = { wsc, wsc };
      f32x2 p0 = { (float)( v.x        & 0xff), (float)((v.x >>  8) & 0xff) };
      f32x2 p1 = { (float)((v.x >> 16) & 0xff), (float)( v.x >> 24)         };
      f32x2 p2 = { (float)( v.y        & 0xff), (float)((v.y >>  8) & 0xff) };
      f32x2 p3 = { (float)((v.y >> 16) & 0xff), (float)( v.y >> 24)         };
      acc2[0] += w2 * p0;
      acc2[1] += w2 * p1;
      acc2[2] += w2 * p2;
      acc2[3] += w2 * p3;
    }
  }
  if (sb < e1){                             // guarded tail (cnt%8 slots)
    #pragma unroll
    for (int t = 0; t < 4; ++t){
      const int e = sb + q2 + t*2;
      float2 ecv = (e < e1) ? excol[e] : make_float2(0.f, 0.f);  // voff 0 safe
      const float wsc = ecv.x;
      const unsigned voff = (unsigned)__float_as_int(ecv.y);
      uint2 v = *(const uint2*)(vbase + voff);
      f32x2 w2 = { wsc, wsc };
      f32x2 p0 = { (float)( v.x        & 0xff), (float)((v.x >>  8) & 0xff) };
      f32x2 p1 = { (float)((v.x >> 16) & 0xff), (float)( v.x >> 24)         };
      f32x2 p2 = { (float)( v.y        & 0xff), (float)((v.y >>  8) & 0xff) };
      f32x2 p3 = { (float)((v.y >> 16) & 0xff), (float)( v.y >> 24)         };
      acc2[0] += w2 * p0;
      acc2[1] += w2 * p1;
      acc2[2] += w2 * p2;
      acc2[3] += w2 * p3;
    }
  }

  // reduce across the 2 quarters of this row (stays within the 32-lane half)
  #pragma unroll
  for (int j = 0; j < 4; ++j){
    acc2[j].x += __shfl_xor(acc2[j].x, 16);
    acc2[j].y += __shfl_xor(acc2[j].y, 16);
  }

  // single-pass LN2 stats over the 16-lane dim groups (both rows simultaneously)
  float sx = 0.f, sxx = 0.f;
  #pragma unroll
  for (int j = 0; j < 4; ++j){
    sx  += acc2[j].x + acc2[j].y;
    sxx += acc2[j].x*acc2[j].x + acc2[j].y*acc2[j].y;
  }
  #pragma unroll
  for (int m = 1; m <= 8; m <<= 1){ sx += __shfl_xor(sx, m); sxx += __shfl_xor(sxx, m); }
  const float mean = sx * (1.f/128.f);
  const float var  = sxx * (1.f/128.f) - mean*mean;
  const float rs   = rsqrtf(var + EPS);

  if (q2 == 0){
    float4 g0 = ((const float4*)ln2_g)[lq*2], g1 = ((const float4*)ln2_g)[lq*2+1];
    float4 b0 = ((const float4*)ln2_b)[lq*2], b1 = ((const float4*)ln2_b)[lq*2+1];
    float4 o0, o1;
    o0.x = g0.x*(acc2[0].x-mean)*rs + b0.x; o0.y = g0.y*(acc2[0].y-mean)*rs + b0.y;
    o0.z = g0.z*(acc2[1].x-mean)*rs + b0.z; o0.w = g0.w*(acc2[1].y-mean)*rs + b0.w;
    o1.x = g1.x*(acc2[2].x-mean)*rs + b1.x; o1.y = g1.y*(acc2[2].y-mean)*rs + b1.y;
    o1.z = g1.z*(acc2[3].x-mean)*rs + b1.z; o1.w = g1.w*(acc2[3].y-mean)*rs + b1.w;
    float4* op = (float4*)(out + (size_t)r*DIM + lq*8);
    op[0] = o0; op[1] = o1;
  }
}

extern "C" void kernel_launch(void* const* d_in, const int* in_sizes, int n_in,
                              void* d_out, int out_size, void* d_ws, size_t ws_size,
                              hipStream_t stream){
  const float* query   = (const float*)d_in[0];
  const float* adj_val = (const float*)d_in[1];
  const float* w_W     = (const float*)d_in[2];
  const float* w_b     = (const float*)d_in[3];
  const float* w1_W    = (const float*)d_in[4];
  const float* w1_b    = (const float*)d_in[5];
  const float* w2_W    = (const float*)d_in[6];
  const float* w2_b    = (const float*)d_in[7];
  const float* ln1_g   = (const float*)d_in[8];
  const float* ln1_b   = (const float*)d_in[9];
  const float* ln2_g   = (const float*)d_in[10];
  const float* ln2_b   = (const float*)d_in[11];
  const int*   adj_row = (const int*)d_in[12];
  const int*   adj_col = (const int*)d_in[13];

  const int N = in_sizes[0] / DIM;
  const int E = in_sizes[1];

  char* ws = (char*)d_ws;
  size_t off = 0;
  unsigned char* value_q = (unsigned char*)(ws + off); off += (size_t)N * DIM;
  float* sum1   = (float*)(ws + off); off += (size_t)N * 4;
  float2* s2v   = (float2*)(ws + off); off += (size_t)N * 8;
  int* row_ptr  = (int*)(ws + off);   off += (size_t)(N + 2) * 4;
  float* u1     = (float*)(ws + off); off += DIM * 4;
  float* u2     = (float*)(ws + off); off += DIM * 4;
  float* c12    = (float*)(ws + off); off += 2 * 4;
  off = (off + 63) & ~(size_t)63;
  __hip_bfloat16* wt_bf = (__hip_bfloat16*)(ws + off); off += DIM * DIM * 2;
  off = (off + 63) & ~(size_t)63;
  float2* excol = (float2*)(ws + off);

  setup_kernel<<<65, 256, 0, stream>>>(w_W, w1_W, w1_b, w2_W, w2_b, wt_bf, u1, u2, c12);
  node_kernel<<<(N + 63) / 64, 256, 0, stream>>>(query, wt_bf, w_b, ln1_g, ln1_b,
                                                 u1, u2, c12, value_q, sum1, s2v, N);
  pack_kernel<<<(E/8 + 255) / 256, 256, 0, stream>>>(adj_val, adj_row, adj_col,
                                                     sum1, s2v, excol, row_ptr, N, E);
  edge_kernel<<<(N + 7) / 8, 256, 0, stream>>>(excol, row_ptr, value_q,
                                               ln2_g, ln2_b, (float*)d_out, N);
}

// Round 15
// 94.114 us; speedup vs baseline: 1.0443x; 1.0252x over previous
//
#include <hip/hip_runtime.h>
#include <hip/hip_bf16.h>

typedef __attribute__((ext_vector_type(8))) short short8;
typedef __attribute__((ext_vector_type(8))) unsigned short ushort8;
typedef __attribute__((ext_vector_type(4))) float f32x4;
typedef __attribute__((ext_vector_type(2))) float f32x2;
typedef __attribute__((ext_vector_type(4))) unsigned int uint4v;

#define DIM 128
#define EPS 1e-6f

__device__ __forceinline__ float wave_sum(float v){
  #pragma unroll
  for (int m = 32; m >= 1; m >>= 1) v += __shfl_xor(v, m);
  return v;
}

// block 0 = u1/u2/c12; blocks 1..64 = W^T bf16. (row_ptr lives in pack.)
__global__ void setup_kernel(const float* __restrict__ w_W,
                             const float* __restrict__ w1_W, const float* __restrict__ w1_b,
                             const float* __restrict__ w2_W, const float* __restrict__ w2_b,
                             __hip_bfloat16* __restrict__ wt_bf,
                             float* __restrict__ u1, float* __restrict__ u2,
                             float* __restrict__ c12){
  const int b = blockIdx.x, tid = threadIdx.x;
  if (b == 0){
    __shared__ float p1s[256], p2s[256];
    const int d = tid & 127, half = tid >> 7;       // half 0: j 0..63, half 1: j 64..127
    const float4* w1p = (const float4*)(w1_W + d*DIM + half*64);
    const float4* w2p = (const float4*)(w2_W + d*DIM + half*64);
    float s1 = 0.f, s2 = 0.f;
    #pragma unroll 4
    for (int j = 0; j < 16; ++j){
      float4 a = w1p[j]; s1 += (a.x + a.y) + (a.z + a.w);
      float4 c = w2p[j]; s2 += (c.x + c.y) + (c.z + c.w);
    }
    p1s[tid] = s1; p2s[tid] = s2;
    __syncthreads();
    if (tid < 128){ u1[tid] = p1s[tid] + p1s[tid+128]; u2[tid] = p2s[tid] + p2s[tid+128]; }
    if (tid < 64){
      float c1 = w1_b[tid] + w1_b[tid + 64];
      float c2 = w2_b[tid] + w2_b[tid + 64];
      c1 = wave_sum(c1); c2 = wave_sum(c2);
      if (tid == 0){ c12[0] = c1; c12[1] = c2; }
    }
  } else {
    int idx = (b - 1) * 256 + tid;
    int j = idx >> 7, d = idx & 127;
    wt_bf[idx] = __float2bfloat16(w_W[d*DIM + j]);
  }
}

// LN1 (16-lane group per node) + value = q@w_W + w_b (bf16 MFMA; wave = 32 rows x 64 cols)
// + per-row int8 quantization of value. Writes sum1, s2v = {tanh2, scale}.
__launch_bounds__(256)
__global__ void node_kernel(const float* __restrict__ query,
                            const __hip_bfloat16* __restrict__ wt_bf,
                            const float* __restrict__ w_b,
                            const float* __restrict__ ln1_g, const float* __restrict__ ln1_b,
                            const float* __restrict__ u1, const float* __restrict__ u2,
                            const float* __restrict__ c12,
                            unsigned char* __restrict__ value_q,
                            float* __restrict__ sum1, float2* __restrict__ s2v, int N){
  __shared__ __hip_bfloat16 A[64][136];    // +8 pad; row stride 272B (16B aligned)
  const int tid  = threadIdx.x;
  const int lane = tid & 63;
  const int w    = tid >> 6;
  const int q16  = lane >> 4;    // group 0..3
  const int lq   = lane & 15;    // lane in group
  const int base = blockIdx.x * 64;

  float uu1[8], uu2[8], gg[8], bv[8];
  {
    const float* p1 = u1 + lq*8; const float* p2 = u2 + lq*8;
    const float* pg = ln1_g + lq*8; const float* pb = ln1_b + lq*8;
    #pragma unroll
    for (int j = 0; j < 8; ++j){ uu1[j]=p1[j]; uu2[j]=p2[j]; gg[j]=pg[j]; bv[j]=pb[j]; }
  }
  const float c1 = c12[0], c2 = c12[1];

  // LN1: group q16 of wave w handles node base + w*16 + it*4 + q16
  #pragma unroll
  for (int it = 0; it < 4; ++it){
    const int row = w*16 + it*4 + q16;
    const int n   = base + row;
    float x[8];
    if (n < N){
      const float4* qp = (const float4*)(query + (size_t)n*DIM + lq*8);
      float4 a = qp[0], b = qp[1];
      x[0]=a.x; x[1]=a.y; x[2]=a.z; x[3]=a.w;
      x[4]=b.x; x[5]=b.y; x[6]=b.z; x[7]=b.w;
    } else {
      #pragma unroll
      for (int j = 0; j < 8; ++j) x[j] = 0.f;
    }
    float s = 0.f, s2 = 0.f;
    #pragma unroll
    for (int j = 0; j < 8; ++j){ s += x[j]; s2 += x[j]*x[j]; }
    #pragma unroll
    for (int m = 1; m <= 8; m <<= 1){ s += __shfl_xor(s, m); s2 += __shfl_xor(s2, m); }
    const float mean = s * (1.f/128.f);
    const float var  = s2 * (1.f/128.f) - mean*mean;
    const float rs   = rsqrtf(var + EPS);

    float p1 = 0.f, p2 = 0.f;
    unsigned pk[4];
    #pragma unroll
    for (int j = 0; j < 4; ++j){
      float n0 = gg[2*j]   * (x[2*j]   - mean) * rs + bv[2*j];
      float n1 = gg[2*j+1] * (x[2*j+1] - mean) * rs + bv[2*j+1];
      p1 += n0*uu1[2*j] + n1*uu1[2*j+1];
      p2 += n0*uu2[2*j] + n1*uu2[2*j+1];
      union { __hip_bfloat16 h; unsigned short u; } a_, b_;
      a_.h = __float2bfloat16(n0); b_.h = __float2bfloat16(n1);
      pk[j] = ((unsigned)b_.u << 16) | (unsigned)a_.u;
    }
    uint4v pv = { pk[0], pk[1], pk[2], pk[3] };
    *(uint4v*)&A[row][lq*8] = pv;
    #pragma unroll
    for (int m = 1; m <= 8; m <<= 1){ p1 += __shfl_xor(p1, m); p2 += __shfl_xor(p2, m); }
    // branchless dual-tanh: lanes 0/1 each compute one tanh in parallel
    if (lq < 2 && n < N){
      const float arg = (lq == 0) ? (p1 + c1) : (p2 + c2);
      const float th = tanhf(arg);
      if (lq == 0) sum1[n] = th;
      else        s2v[n].x = th;
    }
  }
  __syncthreads();

  // GEMM: wave w: rows [(w&1)*32, +32) x cols [(w>>1)*64, +64); 2 MFMA per B-load
  const int rh = (w & 1) * 32;
  const int ch = (w >> 1) * 64;
  short8 afr[2][4];
  #pragma unroll
  for (int m = 0; m < 2; ++m)
    #pragma unroll
    for (int ks = 0; ks < 4; ++ks)
      afr[m][ks] = *(const short8*)&A[rh + m*16 + lq][ks*32 + q16*8];
  __syncthreads();   // all waves done reading A before C overwrites it

  #pragma unroll
  for (int jj = 0; jj < 4; ++jj){
    const int colb = ch + jj*16;
    f32x4 acc[2];
    acc[0] = (f32x4){0.f,0.f,0.f,0.f};
    acc[1] = (f32x4){0.f,0.f,0.f,0.f};
    #pragma unroll
    for (int ks = 0; ks < 4; ++ks){
      short8 bfr = *(const short8*)(wt_bf + (size_t)(colb + lq)*DIM + ks*32 + q16*8);
      acc[0] = __builtin_amdgcn_mfma_f32_16x16x32_bf16(afr[0][ks], bfr, acc[0], 0, 0, 0);
      acc[1] = __builtin_amdgcn_mfma_f32_16x16x32_bf16(afr[1][ks], bfr, acc[1], 0, 0, 0);
    }
    const int col  = colb + lq;            // C/D: col = lane&15, row = (lane>>4)*4 + reg
    const float bias = w_b[col];
    #pragma unroll
    for (int m = 0; m < 2; ++m)
      #pragma unroll
      for (int i = 0; i < 4; ++i)
        A[rh + m*16 + q16*4 + i][col] = __float2bfloat16(acc[m][i] + bias);
  }
  __syncthreads();

  // int8 quantize + store: 4 threads per row; vectorized ds_read_b128 (16B x4)
  const int row = tid >> 2, seg = tid & 3;
  const int n = base + row;
  float vals[32];
  float amax = 0.f;
  const ushort8* ap = (const ushort8*)&A[row][seg*32];
  #pragma unroll
  for (int h = 0; h < 4; ++h){
    ushort8 vv = ap[h];
    #pragma unroll
    for (int j = 0; j < 8; ++j){
      float f = __uint_as_float((unsigned)vv[j] << 16);
      vals[h*8 + j] = f;
      amax = fmaxf(amax, fabsf(f));
    }
  }
  amax = fmaxf(amax, __shfl_xor(amax, 1));
  amax = fmaxf(amax, __shfl_xor(amax, 2));
  const float qs = amax > 0.f ? 127.f / amax : 0.f;
  if (n < N){
    if (seg == 0) s2v[n].y = amax * (1.f/127.f);
    unsigned dw[8];
    #pragma unroll
    for (int d = 0; d < 8; ++d){
      unsigned q0 = (unsigned)__float2int_rn(fmaf(vals[4*d+0], qs, 128.f));
      unsigned q1 = (unsigned)__float2int_rn(fmaf(vals[4*d+1], qs, 128.f));
      unsigned q2 = (unsigned)__float2int_rn(fmaf(vals[4*d+2], qs, 128.f));
      unsigned q3 = (unsigned)__float2int_rn(fmaf(vals[4*d+3], qs, 128.f));
      dw[d] = q0 | (q1 << 8) | (q2 << 16) | (q3 << 24);
    }
    uint4v* dst = (uint4v*)(value_q + (size_t)n*DIM + seg*32);
    dst[0] = (uint4v){dw[0], dw[1], dw[2], dw[3]};
    dst[1] = (uint4v){dw[4], dw[5], dw[6], dw[7]};
  }
}

// 4 edges/thread, vectorized: int4/float4 loads, 4 independent s2v gathers in
// flight, float4 excol stores. Also builds row_ptr via boundary detect (adj_row
// sorted). Per-edge math identical (order-preserved) to the 1-edge version.
__global__ void pack_kernel(const float* __restrict__ adj_val, const int* __restrict__ adj_row,
                            const int* __restrict__ adj_col,
                            const float* __restrict__ sum1, const float2* __restrict__ s2v,
                            float2* __restrict__ excol, int* __restrict__ row_ptr,
                            int N, int E){
  const int e4 = (blockIdx.x * 256 + threadIdx.x) * 4;
  if (e4 >= E) return;

  if (e4 + 3 < E){
    const int4   rr = *(const int4*)(adj_row + e4);
    const float4 av = *(const float4*)(adj_val + e4);
    const int4   cc = *(const int4*)(adj_col + e4);

    // row_ptr boundaries (adj_row sorted)
    const int prev = (e4 > 0) ? adj_row[e4 - 1] : -1;
    if (prev != rr.x) for (int t = prev + 1; t <= rr.x; ++t) row_ptr[t] = e4;
    if (rr.y != rr.x) for (int t = rr.x + 1; t <= rr.y; ++t) row_ptr[t] = e4 + 1;
    if (rr.z != rr.y) for (int t = rr.y + 1; t <= rr.z; ++t) row_ptr[t] = e4 + 2;
    if (rr.w != rr.z) for (int t = rr.z + 1; t <= rr.w; ++t) row_ptr[t] = e4 + 3;
    if (e4 + 4 >= E)  for (int t = rr.w + 1; t <= N;    ++t) row_ptr[t] = E;

    // 4 independent gathers
    const float2 sv0 = s2v[cc.x];
    const float2 sv1 = s2v[cc.y];
    const float2 sv2 = s2v[cc.z];
    const float2 sv3 = s2v[cc.w];
    const float s10 = sum1[rr.x];
    const float s11 = sum1[rr.y];
    const float s12 = sum1[rr.z];
    const float s13 = sum1[rr.w];

    float x0 = av.x * (s10 + sv0.x); float l0 = x0 > 0.f ? x0 : 0.2f * x0;
    float x1 = av.y * (s11 + sv1.x); float l1 = x1 > 0.f ? x1 : 0.2f * x1;
    float x2 = av.z * (s12 + sv2.x); float l2 = x2 > 0.f ? x2 : 0.2f * x2;
    float x3 = av.w * (s13 + sv3.x); float l3 = x3 > 0.f ? x3 : 0.2f * x3;

    float4* dst = (float4*)(excol + e4);
    dst[0] = make_float4(__expf(l0) * sv0.y, __int_as_float(cc.x << 7),
                         __expf(l1) * sv1.y, __int_as_float(cc.y << 7));
    dst[1] = make_float4(__expf(l2) * sv2.y, __int_as_float(cc.z << 7),
                         __expf(l3) * sv3.y, __int_as_float(cc.w << 7));
  } else {
    // generic tail (E not multiple of 4)
    int last_r = -1;
    for (int e = e4; e < E; ++e){
      const int r = adj_row[e];
      const int prev = (e > 0) ? adj_row[e - 1] : -1;
      if (prev != r) for (int t = prev + 1; t <= r; ++t) row_ptr[t] = e;
      const int c = adj_col[e];
      const float2 sv = s2v[c];
      const float x = adj_val[e] * (sum1[r] + sv.x);
      const float lg = x > 0.f ? x : 0.2f * x;
      excol[e] = make_float2(__expf(lg) * sv.y, __int_as_float(c << 7));
      last_r = r;
    }
    if (last_r >= 0) for (int t = last_r + 1; t <= N; ++t) row_ptr[t] = E;
  }
}

// TWO rows per wave (lanes 0-31 = row A, 32-63 = row B); 2 sixteen-lane quarters
// per row -> block granularity 8 edges; R11-exact loop (proven: compiler pipelines
// the 4 unrolled chains; deeper variants serialize — R13 lesson). Single pass
// (LN2 scale-invariance cancels softmax 1/s; +128 quant offset cancels in
// mean-subtraction). All shuffles stay within 32-lane halves.
__launch_bounds__(256)
__global__ void edge_kernel(const float2* __restrict__ excol, const int* __restrict__ row_ptr,
                            const unsigned char* __restrict__ value_q,
                            const float* __restrict__ ln2_g, const float* __restrict__ ln2_b,
                            float* __restrict__ out, int N){
  const int lane = threadIdx.x & 63;
  const int half = lane >> 5;          // row within the wave's pair
  const int ll   = lane & 31;
  const int q2   = ll >> 4;            // quarter within row (0/1)
  const int lq   = ll & 15;            // owns dims [8*lq, 8*lq+8)
  const int r = blockIdx.x * 8 + (threadIdx.x >> 6) * 2 + half;
  if (r >= N) return;
  const int2 rp = *(const int2*)(row_ptr + r);   // e0, e1
  const int e0 = rp.x, e1 = rp.y;
  const unsigned char* vbase = value_q + lq*8;

  f32x2 acc2[4];
  #pragma unroll
  for (int j = 0; j < 4; ++j) acc2[j] = (f32x2){0.f, 0.f};

  int sb = e0;
  for (; sb + 8 <= e1; sb += 8){           // full 8-blocks: no guards
    #pragma unroll
    for (int t = 0; t < 4; ++t){
      float2 ecv = excol[sb + q2 + t*2];
      const float wsc = ecv.x;
      const unsigned voff = (unsigned)__float_as_int(ecv.y);
      uint2 v = *(const uint2*)(vbase + voff);
      f32x2 w2 = { wsc, wsc };
      f32x2 p0 = { (float)( v.x        & 0xff), (float)((v.x >>  8) & 0xff) };
      f32x2 p1 = { (float)((v.x >> 16) & 0xff), (float)( v.x >> 24)         };
      f32x2 p2 = { (float)( v.y        & 0xff), (float)((v.y >>  8) & 0xff) };
      f32x2 p3 = { (float)((v.y >> 16) & 0xff), (float)( v.y >> 24)         };
      acc2[0] += w2 * p0;
      acc2[1] += w2 * p1;
      acc2[2] += w2 * p2;
      acc2[3] += w2 * p3;
    }
  }
  if (sb < e1){                             // guarded tail (cnt%8 slots)
    #pragma unroll
    for (int t = 0; t < 4; ++t){
      const int e = sb + q2 + t*2;
      float2 ecv = (e < e1) ? excol[e] : make_float2(0.f, 0.f);  // voff 0 safe
      const float wsc = ecv.x;
      const unsigned voff = (unsigned)__float_as_int(ecv.y);
      uint2 v = *(const uint2*)(vbase + voff);
      f32x2 w2 = { wsc, wsc };
      f32x2 p0 = { (float)( v.x        & 0xff), (float)((v.x >>  8) & 0xff) };
      f32x2 p1 = { (float)((v.x >> 16) & 0xff), (float)( v.x >> 24)         };
      f32x2 p2 = { (float)( v.y        & 0xff), (float)((v.y >>  8) & 0xff) };
      f32x2 p3 = { (float)((v.y >> 16) & 0xff), (float)( v.y >> 24)         };
      acc2[0] += w2 * p0;
      acc2[1] += w2 * p1;
      acc2[2] += w2 * p2;
      acc2[3] += w2 * p3;
    }
  }

  // reduce across the 2 quarters of this row (stays within the 32-lane half)
  #pragma unroll
  for (int j = 0; j < 4; ++j){
    acc2[j].x += __shfl_xor(acc2[j].x, 16);
    acc2[j].y += __shfl_xor(acc2[j].y, 16);
  }

  // single-pass LN2 stats over the 16-lane dim groups (both rows simultaneously)
  float sx = 0.f, sxx = 0.f;
  #pragma unroll
  for (int j = 0; j < 4; ++j){
    sx  += acc2[j].x + acc2[j].y;
    sxx += acc2[j].x*acc2[j].x + acc2[j].y*acc2[j].y;
  }
  #pragma unroll
  for (int m = 1; m <= 8; m <<= 1){ sx += __shfl_xor(sx, m); sxx += __shfl_xor(sxx, m); }
  const float mean = sx * (1.f/128.f);
  const float var  = sxx * (1.f/128.f) - mean*mean;
  const float rs   = rsqrtf(var + EPS);

  if (q2 == 0){
    float4 g0 = ((const float4*)ln2_g)[lq*2], g1 = ((const float4*)ln2_g)[lq*2+1];
    float4 b0 = ((const float4*)ln2_b)[lq*2], b1 = ((const float4*)ln2_b)[lq*2+1];
    float4 o0, o1;
    o0.x = g0.x*(acc2[0].x-mean)*rs + b0.x; o0.y = g0.y*(acc2[0].y-mean)*rs + b0.y;
    o0.z = g0.z*(acc2[1].x-mean)*rs + b0.z; o0.w = g0.w*(acc2[1].y-mean)*rs + b0.w;
    o1.x = g1.x*(acc2[2].x-mean)*rs + b1.x; o1.y = g1.y*(acc2[2].y-mean)*rs + b1.y;
    o1.z = g1.z*(acc2[3].x-mean)*rs + b1.z; o1.w = g1.w*(acc2[3].y-mean)*rs + b1.w;
    float4* op = (float4*)(out + (size_t)r*DIM + lq*8);
    op[0] = o0; op[1] = o1;
  }
}

extern "C" void kernel_launch(void* const* d_in, const int* in_sizes, int n_in,
                              void* d_out, int out_size, void* d_ws, size_t ws_size,
                              hipStream_t stream){
  const float* query   = (const float*)d_in[0];
  const float* adj_val = (const float*)d_in[1];
  const float* w_W     = (const float*)d_in[2];
  const float* w_b     = (const float*)d_in[3];
  const float* w1_W    = (const float*)d_in[4];
  const float* w1_b    = (const float*)d_in[5];
  const float* w2_W    = (const float*)d_in[6];
  const float* w2_b    = (const float*)d_in[7];
  const float* ln1_g   = (const float*)d_in[8];
  const float* ln1_b   = (const float*)d_in[9];
  const float* ln2_g   = (const float*)d_in[10];
  const float* ln2_b   = (const float*)d_in[11];
  const int*   adj_row = (const int*)d_in[12];
  const int*   adj_col = (const int*)d_in[13];

  const int N = in_sizes[0] / DIM;
  const int E = in_sizes[1];

  char* ws = (char*)d_ws;
  size_t off = 0;
  unsigned char* value_q = (unsigned char*)(ws + off); off += (size_t)N * DIM;
  float* sum1   = (float*)(ws + off); off += (size_t)N * 4;
  float2* s2v   = (float2*)(ws + off); off += (size_t)N * 8;
  int* row_ptr  = (int*)(ws + off);   off += (size_t)(N + 2) * 4;
  float* u1     = (float*)(ws + off); off += DIM * 4;
  float* u2     = (float*)(ws + off); off += DIM * 4;
  float* c12    = (float*)(ws + off); off += 2 * 4;
  off = (off + 63) & ~(size_t)63;
  __hip_bfloat16* wt_bf = (__hip_bfloat16*)(ws + off); off += DIM * DIM * 2;
  off = (off + 63) & ~(size_t)63;
  float2* excol = (float2*)(ws + off);

  setup_kernel<<<65, 256, 0, stream>>>(w_W, w1_W, w1_b, w2_W, w2_b, wt_bf, u1, u2, c12);
  node_kernel<<<(N + 63) / 64, 256, 0, stream>>>(query, wt_bf, w_b, ln1_g, ln1_b,
                                                 u1, u2, c12, value_q, sum1, s2v, N);
  pack_kernel<<<(E/4 + 255) / 256, 256, 0, stream>>>(adj_val, adj_row, adj_col,
                                                     sum1, s2v, excol, row_ptr, N, E);
  edge_kernel<<<(N + 7) / 8, 256, 0, stream>>>(excol, row_ptr, value_q,
                                               ln2_g, ln2_b, (float*)d_out, N);
}